// Round 10
// baseline (386.361 us; speedup 1.0000x reference)
//
#include <hip/hip_runtime.h>
#include <hip/hip_bf16.h>
#include <stdint.h>

// GWNN: out = L2(relu(L1(x))),  L(x) = W_wav · diag(f) · W_inv · (x·W)
// R10: big GEMMs (8192x128x8192) keep the proven R2 skeleton (BM=32, grid 256,
// A fp32 via gload_lds NBUF=6 ring, 1 barrier + counted vmcnt per K-step) but
// the B operand bypasses LDS entirely: B fragments are wave-private, stored in
// ws in FRAGMENT-MAJOR layout (BF[k>>5][ng][lane][8] shorts) so each wave's
// B-frag is ONE fully-coalesced 1KB global load (L2/L3-hit), double-buffered
// in named VGPR sets. LDS traffic/step drops 72KB -> 40KB (the co-bottleneck
// identified across R2-R9); R8 already showed B-direct fails only when the
// addresses scatter - here they are linear in lane.

typedef __attribute__((ext_vector_type(4))) float f32x4;
typedef __attribute__((ext_vector_type(8))) short s16x8;
typedef __attribute__((ext_vector_type(4))) short s16x4;

#define DEVI static __device__ __forceinline__

DEVI short bf1(float x){ __bf16 h = (__bf16)x; return __builtin_bit_cast(short, h); }

DEVI s16x8 cvt8(f32x4 lo, f32x4 hi){
  s16x8 r;
#pragma unroll
  for (int i = 0; i < 4; ++i){ r[i] = bf1(lo[i]); r[4+i] = bf1(hi[i]); }
  return r;
}

DEVI void glds16(const void* g, void* l){
  __builtin_amdgcn_global_load_lds((const __attribute__((address_space(1))) void*)g,
                                   (__attribute__((address_space(3))) void*)l, 16, 0, 0);
}

template<int N> DEVI void waitvm(){
  if constexpr (N == 0)      asm volatile("s_waitcnt vmcnt(0)" ::: "memory");
  else if constexpr (N == 4) asm volatile("s_waitcnt vmcnt(4)" ::: "memory");
  else if constexpr (N == 5) asm volatile("s_waitcnt vmcnt(5)" ::: "memory");
  else if constexpr (N == 6) asm volatile("s_waitcnt vmcnt(6)" ::: "memory");
  else if constexpr (N == 8) asm volatile("s_waitcnt vmcnt(8)" ::: "memory");
}

// BF layout (shorts): element (n, k) of Bt lives at
//   ((k>>5)*8 + (n>>4))*512 + (((k>>3)&3)*16 + (n&15))*8 + (k&7)
// Wave w, step t, frag (kf, ni) = 64 lanes x 8 shorts, linear in lane:
//   base + (t*16 + kf*8 + w*2 + ni)*512 + lane*8

// ============================================================================
// Big GEMM: C[M,128] = A[M,K](f32, cvt->bf16 at LDS read) @ BF^T
// OUTM: 0 f32 row-major, 1 bf16 row-major (RELU), 2 BF-layout (SCALE).
// ============================================================================
template<bool SCALE, bool RELU, int OUTM>
__global__ __launch_bounds__(256, 1) void ggemm(
    const float* __restrict__ Ap, const short* __restrict__ Btp,
    const float* __restrict__ fp, void* __restrict__ Outp, int K, int M)
{
  constexpr int BM = 32, BK = 64;
  constexpr int ASZ = BM*BK*4;     // 8 KB fp32 A tile
  constexpr int NBUF = 6;          // 48 KB LDS, stage-ahead 4 (reuse dist 6)
  __shared__ uint8_t lds[NBUF*ASZ];

  const int tid  = threadIdx.x;
  const int lane = tid & 63;
  const int wv   = tid >> 6;
  const int la   = lane & 15;
  const int g4   = lane >> 4;
  const int m0   = blockIdx.x * BM;

  // ---- A staging (global src pre-swizzled, LDS dest linear) — proven R2 path
  const int r0 = (wv<<3) + (lane>>4);
  const int r1 = r0 + 4;
  const float* gA0 = Ap + (size_t)(m0+r0)*K + (((lane&15)^(r0&15))<<2);
  const float* gA1 = Ap + (size_t)(m0+r1)*K + (((lane&15)^(r1&15))<<2);

  // ---- A fragment LDS offsets (XOR-swizzled reads)
  int aoff[2][2][2];   // [mi][kf][part]
#pragma unroll
  for (int mi = 0; mi < 2; ++mi){
    const int r = mi*16 + la;
#pragma unroll
    for (int kf = 0; kf < 2; ++kf){
      const int v0 = kf*8 + (g4<<1);
      aoff[mi][kf][0] = r*256 + (((v0  )^(r&15))<<4);
      aoff[mi][kf][1] = r*256 + (((v0+1)^(r&15))<<4);
    }
  }

  // ---- B fragment base (fully coalesced: addr linear in lane)
  const short* gB = Btp + (size_t)(wv<<10) + (lane<<3);

  f32x4 acc[2][2] = {};
  s16x8 Be[4], Bo[4];              // [2*kf+ni], named double-buffer

  uint8_t* const lend = lds + NBUF*ASZ;
  uint8_t* bs = lds;
  uint8_t* bc = lds;

  auto STAGE = [&](){              // 2 gload_lds per wave
    glds16(gA0, bs + (wv<<11));
    glds16(gA1, bs + (wv<<11) + 1024);
    gA0 += BK; gA1 += BK;
    bs += ASZ; if (bs == lend) bs = lds;
  };
  auto LOADB = [&](s16x8* B, int t){    // 4 coalesced 1KB loads per wave
    const short* p = gB + (size_t)t*8192;
    B[0] = *(const s16x8*)(p);          // kf0 ni0
    B[1] = *(const s16x8*)(p + 512);    // kf0 ni1
    B[2] = *(const s16x8*)(p + 4096);   // kf1 ni0
    B[3] = *(const s16x8*)(p + 4608);   // kf1 ni1
  };
  auto COMPUTE = [&](const s16x8* B){
    const uint8_t* buf = bc;
#pragma unroll
    for (int kf = 0; kf < 2; ++kf){
      s16x8 a0 = cvt8(*(const f32x4*)(buf + aoff[0][kf][0]),
                      *(const f32x4*)(buf + aoff[0][kf][1]));
      s16x8 a1 = cvt8(*(const f32x4*)(buf + aoff[1][kf][0]),
                      *(const f32x4*)(buf + aoff[1][kf][1]));
      acc[0][0] = __builtin_amdgcn_mfma_f32_16x16x32_bf16(a0, B[2*kf  ], acc[0][0], 0, 0, 0);
      acc[0][1] = __builtin_amdgcn_mfma_f32_16x16x32_bf16(a0, B[2*kf+1], acc[0][1], 0, 0, 0);
      acc[1][0] = __builtin_amdgcn_mfma_f32_16x16x32_bf16(a1, B[2*kf  ], acc[1][0], 0, 0, 0);
      acc[1][1] = __builtin_amdgcn_mfma_f32_16x16x32_bf16(a1, B[2*kf+1], acc[1][1], 0, 0, 0);
    }
    bc += ASZ; if (bc == lend) bc = lds;
  };

  const int ns = K >> 6;           // 128 here; requires ns even, >= 8

  // prologue: A(0..3) then B(0)
  STAGE(); STAGE(); STAGE(); STAGE();
  LOADB(Be, 0);

  for (int t = 0; t < ns; t += 2){
    // ---- even iter t: compute Be
    LOADB(Bo, t+1);
    asm volatile("" ::: "memory");        // pin order: B(t+1) before A(t+4)
    if (t + 4 < ns) STAGE();
    if (t == 0 || t == ns-4) waitvm<6>();
    else if (t == ns-2)      waitvm<4>();
    else                     waitvm<8>();
    __builtin_amdgcn_s_barrier();
    asm volatile("" ::: "memory");
    COMPUTE(Be);
    asm volatile("" ::: "memory");
    // ---- odd iter u = t+1: compute Bo
    const int u = t + 1;
    if (u + 1 < ns) LOADB(Be, u+1);
    asm volatile("" ::: "memory");
    if (u + 4 < ns) STAGE();
    if (u == ns-3)      waitvm<4>();
    else if (u == ns-1) waitvm<0>();
    else                waitvm<8>();
    __builtin_amdgcn_s_barrier();
    asm volatile("" ::: "memory");
    COMPUTE(Bo);
    asm volatile("" ::: "memory");
  }

  // ---- epilogue
  const int mbase = m0 + (g4<<2);
  const int nc0   = (wv<<5) + la;
  f32x4 fv0, fv1;
  if constexpr (SCALE){
    fv0 = *(const f32x4*)(fp + mbase);
    fv1 = *(const f32x4*)(fp + mbase + 16);
  }
  const int bx = blockIdx.x;
#pragma unroll
  for (int mi = 0; mi < 2; ++mi){
#pragma unroll
    for (int ni = 0; ni < 2; ++ni){
      f32x4 v = acc[mi][ni];
      if constexpr (SCALE) v = v * (mi ? fv1 : fv0);
      if constexpr (RELU){
#pragma unroll
        for (int r = 0; r < 4; ++r) v[r] = fmaxf(v[r], 0.0f);
      }
      if constexpr (OUTM == 2){
        s16x4 pk;
#pragma unroll
        for (int r = 0; r < 4; ++r) pk[r] = bf1(v[r]);
        const int blk   = (bx<<3) + (wv<<1) + ni;
        const int inner = ((((mi<<1) + (g4>>1)) & 3)<<7) + (la<<3) + ((g4&1)<<2);
        *(s16x4*)((short*)Outp + (size_t)blk*512 + inner) = pk;
      } else if constexpr (OUTM == 1){
#pragma unroll
        for (int r = 0; r < 4; ++r)
          ((short*)Outp)[(size_t)(mbase + (mi<<4) + r)*128 + nc0 + (ni<<4)] = bf1(v[r]);
      } else {
#pragma unroll
        for (int r = 0; r < 4; ++r)
          ((float*)Outp)[(size_t)(mbase + (mi<<4) + r)*128 + nc0 + (ni<<4)] = v[r];
      }
    }
  }
}

// ============================================================================
// Small K=128 GEMM (proven LDS-B path): out = BF layout.
// A = fp32 (ABF=0) or bf16 row-major (ABF=1); B = Wt[n][k].
// ============================================================================
template<bool ABF>
__global__ __launch_bounds__(256, 1) void sgemm(
    const void* __restrict__ Ap, const short* __restrict__ Btp,
    void* __restrict__ Outp, int K, int M)
{
  constexpr int BM = 32, BN = 128, BK = 64;
  constexpr int ASZ = ABF ? BM*BK*2 : BM*BK*4;
  constexpr int BSZ = BN*BK*2;
  constexpr int TSZ = ASZ + BSZ;
  constexpr int NL  = ABF ? 5 : 6;
  constexpr int NBUF = 3, PRE = 2;
  __shared__ uint8_t lds[NBUF*TSZ];

  const int tid  = threadIdx.x;
  const int lane = tid & 63;
  const int wv   = tid >> 6;
  const int la   = lane & 15;
  const int g4   = lane >> 4;
  const int m0   = blockIdx.x * BM;

  const float* gA0 = nullptr; const float* gA1 = nullptr; const short* gAh = nullptr;
  if constexpr (!ABF){
    const float* Af = (const float*)Ap;
    int r0 = (wv<<3) + (lane>>4);
    int r1 = r0 + 4;
    gA0 = Af + (size_t)(m0+r0)*K + (((lane&15)^(r0&15))<<2);
    gA1 = Af + (size_t)(m0+r1)*K + (((lane&15)^(r1&15))<<2);
  } else {
    const short* Ah = (const short*)Ap;
    int r = (wv<<3) + (lane>>3);
    gAh = Ah + (size_t)(m0+r)*K + (((lane&7)^(r&7))<<3);
  }
  const int nb0 = (wv<<5) + (lane>>3);
  const short* gB0 = Btp + (size_t)(nb0    )*K + (((lane&7)^(nb0&7))<<3);
  const short* gB1 = Btp + (size_t)(nb0+ 8 )*K + (((lane&7)^(nb0&7))<<3);
  const short* gB2 = Btp + (size_t)(nb0+16 )*K + (((lane&7)^(nb0&7))<<3);
  const short* gB3 = Btp + (size_t)(nb0+24 )*K + (((lane&7)^(nb0&7))<<3);

  int aoff[2][2][2];
  int boff[2][2];
#pragma unroll
  for (int mi = 0; mi < 2; ++mi){
    const int r = mi*16 + la;
#pragma unroll
    for (int kf = 0; kf < 2; ++kf){
      if constexpr (!ABF){
        const int v0 = kf*8 + (g4<<1);
        aoff[mi][kf][0] = r*256 + (((v0  )^(r&15))<<4);
        aoff[mi][kf][1] = r*256 + (((v0+1)^(r&15))<<4);
      } else {
        const int u = kf*4 + g4;
        aoff[mi][kf][0] = r*128 + ((u^(r&7))<<4);
        aoff[mi][kf][1] = 0;
      }
    }
  }
#pragma unroll
  for (int ni = 0; ni < 2; ++ni){
    const int n = (wv<<5) + ni*16 + la;
#pragma unroll
    for (int kf = 0; kf < 2; ++kf){
      const int u = kf*4 + g4;
      boff[ni][kf] = n*128 + ((u^(n&7))<<4);
    }
  }

  f32x4 acc[2][2] = {};

  auto STAGE = [&](uint8_t* buf){
    uint8_t* Ab = buf;
    uint8_t* Bb = buf + ASZ;
    if constexpr (!ABF){
      glds16(gA0, Ab + (wv<<11));
      glds16(gA1, Ab + (wv<<11) + 1024);
      gA0 += BK; gA1 += BK;
    } else {
      glds16(gAh, Ab + (wv<<10));
      gAh += BK;
    }
    glds16(gB0, Bb + (wv<<12));
    glds16(gB1, Bb + (wv<<12) + 1024);
    glds16(gB2, Bb + (wv<<12) + 2048);
    glds16(gB3, Bb + (wv<<12) + 3072);
    gB0 += BK; gB1 += BK; gB2 += BK; gB3 += BK;
  };

  auto COMPUTE = [&](const uint8_t* buf){
    const uint8_t* Ab = buf;
    const uint8_t* Bb = buf + ASZ;
#pragma unroll
    for (int kf = 0; kf < 2; ++kf){
      s16x8 a0, a1, b0, b1;
      if constexpr (!ABF){
        a0 = cvt8(*(const f32x4*)(Ab + aoff[0][kf][0]), *(const f32x4*)(Ab + aoff[0][kf][1]));
        a1 = cvt8(*(const f32x4*)(Ab + aoff[1][kf][0]), *(const f32x4*)(Ab + aoff[1][kf][1]));
      } else {
        a0 = *(const s16x8*)(Ab + aoff[0][kf][0]);
        a1 = *(const s16x8*)(Ab + aoff[1][kf][0]);
      }
      b0 = *(const s16x8*)(Bb + boff[0][kf]);
      b1 = *(const s16x8*)(Bb + boff[1][kf]);
      acc[0][0] = __builtin_amdgcn_mfma_f32_16x16x32_bf16(a0, b0, acc[0][0], 0, 0, 0);
      acc[0][1] = __builtin_amdgcn_mfma_f32_16x16x32_bf16(a0, b1, acc[0][1], 0, 0, 0);
      acc[1][0] = __builtin_amdgcn_mfma_f32_16x16x32_bf16(a1, b0, acc[1][0], 0, 0, 0);
      acc[1][1] = __builtin_amdgcn_mfma_f32_16x16x32_bf16(a1, b1, acc[1][1], 0, 0, 0);
    }
  };

  const int ns = K >> 6;
  uint8_t* const lend = lds + NBUF*TSZ;
  uint8_t* bs = lds;
  uint8_t* bc = lds;
  for (int s = 0; s < PRE && s < ns; ++s){
    STAGE(bs);
    bs += TSZ; if (bs == lend) bs = lds;
  }
  for (int t = 0; t < ns; ++t){
    if (t < ns - 1) waitvm<NL>(); else waitvm<0>();
    __builtin_amdgcn_s_barrier();
    asm volatile("" ::: "memory");
    if (t + PRE < ns){
      STAGE(bs);
      bs += TSZ; if (bs == lend) bs = lds;
    }
    COMPUTE(bc);
    bc += TSZ; if (bc == lend) bc = lds;
    asm volatile("" ::: "memory");
  }

  // epilogue -> BF layout
  const int bx = blockIdx.x;
#pragma unroll
  for (int mi = 0; mi < 2; ++mi){
#pragma unroll
    for (int ni = 0; ni < 2; ++ni){
      s16x4 pk;
#pragma unroll
      for (int r = 0; r < 4; ++r) pk[r] = bf1(acc[mi][ni][r]);
      const int blk   = (bx<<3) + (wv<<1) + ni;
      const int inner = ((((mi<<1) + (g4>>1)) & 3)<<7) + (la<<3) + ((g4&1)<<2);
      *(s16x4*)((short*)Outp + (size_t)blk*512 + inner) = pk;
    }
  }
}

// W1T[n][k] = bf16(W1[k][n]), same for W2 — tiny one-shot transpose.
__global__ void wtrans_k(const float* __restrict__ W1, const float* __restrict__ W2,
                         short* __restrict__ T1, short* __restrict__ T2){
  const int idx = blockIdx.x*256 + threadIdx.x;
  const int m = idx >> 14, rem = idx & 16383;
  const int n = rem >> 7, k = rem & 127;
  const float* W = m ? W2 : W1;
  short* T = m ? T2 : T1;
  T[n*128 + k] = bf1(W[k*128 + n]);
}

extern "C" void kernel_launch(void* const* d_in, const int* in_sizes, int n_in,
                              void* d_out, int out_size, void* d_ws, size_t ws_size,
                              hipStream_t stream){
  const float* input = (const float*)d_in[0];
  const float* wav   = (const float*)d_in[1];
  const float* winv  = (const float*)d_in[2];
  const float* W1    = (const float*)d_in[3];
  const float* f1    = (const float*)d_in[4];
  const float* W2    = (const float*)d_in[5];
  const float* f2    = (const float*)d_in[6];

  constexpr int M = 8192;
  uint8_t* ws = (uint8_t*)d_ws;
  short* W1T = (short*)(ws);                        // 32 KB  [n][k]
  short* W2T = (short*)(ws + (32<<10));             // 32 KB  [n][k]
  short* XWT = (short*)(ws + (64<<10));             // 2 MB   BF layout
  short* SPT = (short*)(ws + (64<<10) + (2<<20));   // 2 MB   BF layout
  short* H1  = (short*)(ws + (64<<10) + (4<<20));   // 2 MB   bf16 row-major

  dim3 b(256), g(M/32), gt(128);

  wtrans_k<<<gt, b, 0, stream>>>(W1, W2, W1T, W2T);
  // layer 1
  sgemm<false><<<g, b, 0, stream>>>(input, W1T, XWT, 128, M);
  ggemm<true ,false,2><<<g, b, 0, stream>>>(winv, XWT, f1, SPT, M, M);
  ggemm<false,true ,1><<<g, b, 0, stream>>>(wav,  SPT, nullptr, H1, M, M);
  // layer 2
  sgemm<true ><<<g, b, 0, stream>>>(H1, W2T, XWT, 128, M);
  ggemm<true ,false,2><<<g, b, 0, stream>>>(winv, XWT, f2, SPT, M, M);
  ggemm<false,false,0><<<g, b, 0, stream>>>(wav,  SPT, nullptr, d_out, M, M);
}

// Round 11
// 306.873 us; speedup vs baseline: 1.2590x; 1.2590x over previous
//
#include <hip/hip_runtime.h>
#include <hip/hip_bf16.h>
#include <stdint.h>

// GWNN: out = L2(relu(L1(x))),  L(x) = W_wav · diag(f) · W_inv · (x·W)
// R11: big GEMMs (8192x128x8192) with BM=128 + split-K x4 (grid 64x4 = 256,
// 1 block/CU). Each wave owns 32 rows -> A LDS reads deduplicated; each K-step
// moves 32KB HBM A (~3100cyc) vs ~1700cyc LDS and ~600cyc fixed tax -> the
// HBM drain finally dominates the per-step critical path, and the fixed tax
// amortizes 4x (32 steps vs 128). Pipeline skeleton identical to proven R2:
// NBUF=3 ring, PRE=2, one barrier + counted vmcnt(12)/0 per step.
// f32 partials P[4][M][128]; R7-proven fused reduce kernels (4-way sum).

typedef __attribute__((ext_vector_type(4))) float f32x4;
typedef __attribute__((ext_vector_type(8))) short s16x8;
typedef __attribute__((ext_vector_type(4))) short s16x4;

#define DEVI static __device__ __forceinline__

DEVI short bf1(float x){ __bf16 h = (__bf16)x; return __builtin_bit_cast(short, h); }

DEVI s16x8 cvt8(f32x4 lo, f32x4 hi){
  s16x8 r;
#pragma unroll
  for (int i = 0; i < 4; ++i){ r[i] = bf1(lo[i]); r[4+i] = bf1(hi[i]); }
  return r;
}

DEVI void glds16(const void* g, void* l){
  __builtin_amdgcn_global_load_lds((const __attribute__((address_space(1))) void*)g,
                                   (__attribute__((address_space(3))) void*)l, 16, 0, 0);
}

template<int N> DEVI void waitvm(){
  if constexpr (N == 0)       asm volatile("s_waitcnt vmcnt(0)"  ::: "memory");
  else if constexpr (N == 5)  asm volatile("s_waitcnt vmcnt(5)"  ::: "memory");
  else if constexpr (N == 6)  asm volatile("s_waitcnt vmcnt(6)"  ::: "memory");
  else if constexpr (N == 12) asm volatile("s_waitcnt vmcnt(12)" ::: "memory");
}

// ============================================================================
// Big GEMM, BM=128, split-K x4: P[kq][M][128] = A[M, kq-quarter](f32) @ Bt^T
// Bt bf16 row-major [128][K]. 4 waves; wave w owns rows 32w..32w+31 (all 128
// cols): acc[2][8], 32 MFMA/wave/step, no A-read duplication.
// Per stage per wave: 8 A gload_lds + 4 B gload_lds = 12 vmcnt ops.
// ============================================================================
__global__ __launch_bounds__(256, 1) void gemm_big(
    const float* __restrict__ Ap, const short* __restrict__ Btp,
    float* __restrict__ Pp, int K, int M)
{
  constexpr int BM = 128, BK = 64;
  constexpr int ASZ = BM*BK*4;     // 32 KB fp32 A tile
  constexpr int BSZ = 128*BK*2;    // 16 KB B tile
  constexpr int TSZ = ASZ + BSZ;   // 48 KB
  constexpr int NBUF = 3, PRE = 2; // 144 KB LDS
  __shared__ uint8_t lds[NBUF*TSZ];

  const int tid  = threadIdx.x;
  const int lane = tid & 63;
  const int wv   = tid >> 6;
  const int la   = lane & 15;
  const int g4   = lane >> 4;
  const int m0   = blockIdx.x * BM;
  const int kq   = blockIdx.y;
  const int K4   = K >> 2;
  const int kb   = kq * K4;

  // ---- A staging: wave w, instr j (0..7) stages local rows 32w+4j..+3.
  // Global src pre-swizzled by (row&15); LDS dest linear (HW adds lane*16).
  const float* gAbase = Ap + (size_t)m0*K + kb;
  int aoffg[8];
#pragma unroll
  for (int j = 0; j < 8; ++j){
    const int rl = (wv<<5) + (j<<2) + (lane>>4);        // local row 0..127
    aoffg[j] = rl*K + (((lane&15) ^ (rl&15))<<2);       // float offset
  }

  // ---- B staging (R2-proven): wave w stages rows 32w..32w+31, pre-swizzled
  const int nb0 = (wv<<5) + (lane>>3);
  const short* gB0 = Btp + (size_t)(nb0    )*K + kb + (((lane&7)^(nb0&7))<<3);
  const short* gB1 = Btp + (size_t)(nb0+ 8 )*K + kb + (((lane&7)^(nb0&7))<<3);
  const short* gB2 = Btp + (size_t)(nb0+16 )*K + kb + (((lane&7)^(nb0&7))<<3);
  const short* gB3 = Btp + (size_t)(nb0+24 )*K + kb + (((lane&7)^(nb0&7))<<3);

  // ---- fragment LDS byte offsets (XOR-swizzled reads)
  int aoff[2][2][2];   // [mi][kf][part]; fp32 row = 16 x 16B units
#pragma unroll
  for (int mi = 0; mi < 2; ++mi){
    const int r = (wv<<5) + mi*16 + la;                 // wave-private rows
#pragma unroll
    for (int kf = 0; kf < 2; ++kf){
      const int v0 = kf*8 + (g4<<1);
      aoff[mi][kf][0] = r*256 + (((v0  )^(r&15))<<4);
      aoff[mi][kf][1] = r*256 + (((v0+1)^(r&15))<<4);
    }
  }
  int boff[8][2];      // [ni][kf]; all 128 cols per wave
#pragma unroll
  for (int ni = 0; ni < 8; ++ni){
    const int n = ni*16 + la;
#pragma unroll
    for (int kf = 0; kf < 2; ++kf){
      const int u = kf*4 + g4;
      boff[ni][kf] = n*128 + ((u^(n&7))<<4);
    }
  }

  f32x4 acc[2][8] = {};

  int kk = 0;                                // A k-advance (floats)
  uint8_t* const lend = lds + NBUF*TSZ;
  uint8_t* bs = lds;
  uint8_t* bc = lds;

  auto STAGE = [&](){
    uint8_t* Ab = bs;
    uint8_t* Bb = bs + ASZ;
#pragma unroll
    for (int j = 0; j < 8; ++j)
      glds16(gAbase + aoffg[j] + kk, Ab + (wv<<13) + (j<<10));
    kk += BK;
    glds16(gB0, Bb + (wv<<12));
    glds16(gB1, Bb + (wv<<12) + 1024);
    glds16(gB2, Bb + (wv<<12) + 2048);
    glds16(gB3, Bb + (wv<<12) + 3072);
    gB0 += BK; gB1 += BK; gB2 += BK; gB3 += BK;
    bs += TSZ; if (bs == lend) bs = lds;
  };

  auto COMPUTE = [&](){
    const uint8_t* Ab = bc;
    const uint8_t* Bb = bc + ASZ;
#pragma unroll
    for (int kf = 0; kf < 2; ++kf){
      s16x8 a0 = cvt8(*(const f32x4*)(Ab + aoff[0][kf][0]),
                      *(const f32x4*)(Ab + aoff[0][kf][1]));
      s16x8 a1 = cvt8(*(const f32x4*)(Ab + aoff[1][kf][0]),
                      *(const f32x4*)(Ab + aoff[1][kf][1]));
#pragma unroll
      for (int ni = 0; ni < 8; ++ni){
        s16x8 b = *(const s16x8*)(Bb + boff[ni][kf]);
        acc[0][ni] = __builtin_amdgcn_mfma_f32_16x16x32_bf16(a0, b, acc[0][ni], 0, 0, 0);
        acc[1][ni] = __builtin_amdgcn_mfma_f32_16x16x32_bf16(a1, b, acc[1][ni], 0, 0, 0);
      }
    }
    bc += TSZ; if (bc == lend) bc = lds;
  };

  const int ns = K4 >> 6;                    // 32 steps
  for (int s = 0; s < PRE && s < ns; ++s) STAGE();

  for (int t = 0; t < ns; ++t){
    if (t < ns - 1) waitvm<12>();            // stage t landed; t+1 in flight
    else            waitvm<0>();
    __builtin_amdgcn_s_barrier();
    asm volatile("" ::: "memory");
    if (t + PRE < ns) STAGE();
    COMPUTE();
    asm volatile("" ::: "memory");
  }

  // ---- partial epilogue: f32 P[kq][M][128]
  float* P = Pp + (size_t)kq * M * 128;
  const int rbase = m0 + (wv<<5) + (g4<<2);
#pragma unroll
  for (int mi = 0; mi < 2; ++mi)
#pragma unroll
    for (int ni = 0; ni < 8; ++ni)
#pragma unroll
      for (int r = 0; r < 4; ++r)
        P[(size_t)(rbase + mi*16 + r)*128 + ni*16 + la] = acc[mi][ni][r];
}

// ============================================================================
// Small K=128 GEMM (R7-proven): out = bf16 transposed [128][M].
// ============================================================================
template<bool ABF>
__global__ __launch_bounds__(256, 1) void sgemm(
    const void* __restrict__ Ap, const short* __restrict__ Btp,
    void* __restrict__ Outp, int K, int M)
{
  constexpr int BM = 32, BN = 128, BK = 64;
  constexpr int ASZ = ABF ? BM*BK*2 : BM*BK*4;
  constexpr int BSZ = BN*BK*2;
  constexpr int TSZ = ASZ + BSZ;
  constexpr int NL  = ABF ? 5 : 6;
  constexpr int NBUF = 3, PRE = 2;
  __shared__ uint8_t lds[NBUF*TSZ];

  const int tid  = threadIdx.x;
  const int lane = tid & 63;
  const int wv   = tid >> 6;
  const int la   = lane & 15;
  const int g4   = lane >> 4;
  const int m0   = blockIdx.x * BM;

  const float* gA0 = nullptr; const float* gA1 = nullptr; const short* gAh = nullptr;
  if constexpr (!ABF){
    const float* Af = (const float*)Ap;
    int r0 = (wv<<3) + (lane>>4);
    int r1 = r0 + 4;
    gA0 = Af + (size_t)(m0+r0)*K + (((lane&15)^(r0&15))<<2);
    gA1 = Af + (size_t)(m0+r1)*K + (((lane&15)^(r1&15))<<2);
  } else {
    const short* Ah = (const short*)Ap;
    int r = (wv<<3) + (lane>>3);
    gAh = Ah + (size_t)(m0+r)*K + (((lane&7)^(r&7))<<3);
  }
  const int nb0 = (wv<<5) + (lane>>3);
  const short* gB0 = Btp + (size_t)(nb0    )*K + (((lane&7)^(nb0&7))<<3);
  const short* gB1 = Btp + (size_t)(nb0+ 8 )*K + (((lane&7)^(nb0&7))<<3);
  const short* gB2 = Btp + (size_t)(nb0+16 )*K + (((lane&7)^(nb0&7))<<3);
  const short* gB3 = Btp + (size_t)(nb0+24 )*K + (((lane&7)^(nb0&7))<<3);

  int aoff[2][2][2];
  int boff[2][2];
#pragma unroll
  for (int mi = 0; mi < 2; ++mi){
    const int r = mi*16 + la;
#pragma unroll
    for (int kf = 0; kf < 2; ++kf){
      if constexpr (!ABF){
        const int v0 = kf*8 + (g4<<1);
        aoff[mi][kf][0] = r*256 + (((v0  )^(r&15))<<4);
        aoff[mi][kf][1] = r*256 + (((v0+1)^(r&15))<<4);
      } else {
        const int u = kf*4 + g4;
        aoff[mi][kf][0] = r*128 + ((u^(r&7))<<4);
        aoff[mi][kf][1] = 0;
      }
    }
  }
#pragma unroll
  for (int ni = 0; ni < 2; ++ni){
    const int n = (wv<<5) + ni*16 + la;
#pragma unroll
    for (int kf = 0; kf < 2; ++kf){
      const int u = kf*4 + g4;
      boff[ni][kf] = n*128 + ((u^(n&7))<<4);
    }
  }

  f32x4 acc[2][2] = {};

  auto STAGE = [&](uint8_t* buf){
    uint8_t* Ab = buf;
    uint8_t* Bb = buf + ASZ;
    if constexpr (!ABF){
      glds16(gA0, Ab + (wv<<11));
      glds16(gA1, Ab + (wv<<11) + 1024);
      gA0 += BK; gA1 += BK;
    } else {
      glds16(gAh, Ab + (wv<<10));
      gAh += BK;
    }
    glds16(gB0, Bb + (wv<<12));
    glds16(gB1, Bb + (wv<<12) + 1024);
    glds16(gB2, Bb + (wv<<12) + 2048);
    glds16(gB3, Bb + (wv<<12) + 3072);
    gB0 += BK; gB1 += BK; gB2 += BK; gB3 += BK;
  };

  auto COMPUTE = [&](const uint8_t* buf){
    const uint8_t* Ab = buf;
    const uint8_t* Bb = buf + ASZ;
#pragma unroll
    for (int kf = 0; kf < 2; ++kf){
      s16x8 a0, a1, b0, b1;
      if constexpr (!ABF){
        a0 = cvt8(*(const f32x4*)(Ab + aoff[0][kf][0]), *(const f32x4*)(Ab + aoff[0][kf][1]));
        a1 = cvt8(*(const f32x4*)(Ab + aoff[1][kf][0]), *(const f32x4*)(Ab + aoff[1][kf][1]));
      } else {
        a0 = *(const s16x8*)(Ab + aoff[0][kf][0]);
        a1 = *(const s16x8*)(Ab + aoff[1][kf][0]);
      }
      b0 = *(const s16x8*)(Bb + boff[0][kf]);
      b1 = *(const s16x8*)(Bb + boff[1][kf]);
      acc[0][0] = __builtin_amdgcn_mfma_f32_16x16x32_bf16(a0, b0, acc[0][0], 0, 0, 0);
      acc[0][1] = __builtin_amdgcn_mfma_f32_16x16x32_bf16(a0, b1, acc[0][1], 0, 0, 0);
      acc[1][0] = __builtin_amdgcn_mfma_f32_16x16x32_bf16(a1, b0, acc[1][0], 0, 0, 0);
      acc[1][1] = __builtin_amdgcn_mfma_f32_16x16x32_bf16(a1, b1, acc[1][1], 0, 0, 0);
    }
  };

  const int ns = K >> 6;
  uint8_t* const lend = lds + NBUF*TSZ;
  uint8_t* bs = lds;
  uint8_t* bc = lds;
  for (int s = 0; s < PRE && s < ns; ++s){
    STAGE(bs);
    bs += TSZ; if (bs == lend) bs = lds;
  }
  for (int t = 0; t < ns; ++t){
    if (t < ns - 1) waitvm<NL>(); else waitvm<0>();
    __builtin_amdgcn_s_barrier();
    asm volatile("" ::: "memory");
    if (t + PRE < ns){
      STAGE(bs);
      bs += TSZ; if (bs == lend) bs = lds;
    }
    COMPUTE(bc);
    bc += TSZ; if (bc == lend) bc = lds;
    asm volatile("" ::: "memory");
  }

  const int mbase = m0 + (g4<<2);
  const int nc0   = (wv<<5) + la;
#pragma unroll
  for (int mi = 0; mi < 2; ++mi){
#pragma unroll
    for (int ni = 0; ni < 2; ++ni){
      s16x4 pk;
#pragma unroll
      for (int r = 0; r < 4; ++r) pk[r] = bf1(acc[mi][ni][r]);
      *(s16x4*)((short*)Outp + (size_t)(nc0 + (ni<<4))*M + (mbase + (mi<<4))) = pk;
    }
  }
}

// ============================================================================
// Reduce kernels: combine 4 K-quarter partials P[4][M][128] (f32).
// ============================================================================

// SPT[n][m] = bf16( f[m] * sum_q P[q][m][n] )  — transpose via LDS.
__global__ __launch_bounds__(256) void red_t(
    const float* __restrict__ Pp, const float* __restrict__ fp,
    short* __restrict__ out, int M)
{
  __shared__ short t[128*65];
  const size_t S = (size_t)M*128;
  const int m0 = blockIdx.x * 64;
  const int tid = threadIdx.x;
#pragma unroll
  for (int it = 0; it < 8; ++it){
    const int idx = it*256 + tid;
    const int m = idx >> 5, nq = idx & 31;
    const float* base = Pp + (size_t)(m0+m)*128;
    f32x4 a = ((const f32x4*)(base      ))[nq];
    f32x4 b = ((const f32x4*)(base +   S))[nq];
    f32x4 c = ((const f32x4*)(base + 2*S))[nq];
    f32x4 d = ((const f32x4*)(base + 3*S))[nq];
    const float fv = fp[m0+m];
#pragma unroll
    for (int j = 0; j < 4; ++j)
      t[(nq*4+j)*65 + m] = bf1(fv * ((a[j] + b[j]) + (c[j] + d[j])));
  }
  __syncthreads();
#pragma unroll
  for (int it = 0; it < 8; ++it){
    const int idx = it*256 + tid;
    const int n = idx >> 4, mc = idx & 15;
    s16x4 v;
#pragma unroll
    for (int j = 0; j < 4; ++j) v[j] = t[n*65 + mc*4 + j];
    *(s16x4*)(out + (size_t)n*M + m0 + mc*4) = v;
  }
}

// H1[i] = bf16( relu(sum_q P[q][i]) )  — row-major, linear.
__global__ __launch_bounds__(256) void red_r(
    const float* __restrict__ Pp, short* __restrict__ out, int M)
{
  const size_t S = (size_t)M*128;
  const size_t i0 = (size_t)(blockIdx.x*256 + threadIdx.x) * 8;
  s16x8 v;
#pragma unroll
  for (int h = 0; h < 2; ++h){
    f32x4 a = *(const f32x4*)(Pp + i0 + 4*h);
    f32x4 b = *(const f32x4*)(Pp + i0 + 4*h + S);
    f32x4 c = *(const f32x4*)(Pp + i0 + 4*h + 2*S);
    f32x4 d = *(const f32x4*)(Pp + i0 + 4*h + 3*S);
#pragma unroll
    for (int j = 0; j < 4; ++j)
      v[4*h+j] = bf1(fmaxf((a[j] + b[j]) + (c[j] + d[j]), 0.0f));
  }
  *(s16x8*)(out + i0) = v;
}

// d_out[i] = sum_q P[q][i]  — f32 row-major, linear.
__global__ __launch_bounds__(256) void red_f(
    const float* __restrict__ Pp, float* __restrict__ out, int M)
{
  const size_t S = (size_t)M*128;
  const size_t i0 = (size_t)(blockIdx.x*256 + threadIdx.x) * 4;
  f32x4 a = *(const f32x4*)(Pp + i0);
  f32x4 b = *(const f32x4*)(Pp + i0 + S);
  f32x4 c = *(const f32x4*)(Pp + i0 + 2*S);
  f32x4 d = *(const f32x4*)(Pp + i0 + 3*S);
  *(f32x4*)(out + i0) = (a + b) + (c + d);
}

// W1T[n][k] = bf16(W1[k][n]), same for W2 — tiny one-shot transpose.
__global__ void wtrans_k(const float* __restrict__ W1, const float* __restrict__ W2,
                         short* __restrict__ T1, short* __restrict__ T2){
  const int idx = blockIdx.x*256 + threadIdx.x;
  const int m = idx >> 14, rem = idx & 16383;
  const int n = rem >> 7, k = rem & 127;
  const float* W = m ? W2 : W1;
  short* T = m ? T2 : T1;
  T[n*128 + k] = bf1(W[k*128 + n]);
}

extern "C" void kernel_launch(void* const* d_in, const int* in_sizes, int n_in,
                              void* d_out, int out_size, void* d_ws, size_t ws_size,
                              hipStream_t stream){
  const float* input = (const float*)d_in[0];
  const float* wav   = (const float*)d_in[1];
  const float* winv  = (const float*)d_in[2];
  const float* W1    = (const float*)d_in[3];
  const float* f1    = (const float*)d_in[4];
  const float* W2    = (const float*)d_in[5];
  const float* f2    = (const float*)d_in[6];

  constexpr int M = 8192;
  uint8_t* ws = (uint8_t*)d_ws;
  short* W1T = (short*)(ws);                        // 32 KB  [n][k]
  short* W2T = (short*)(ws + (32<<10));             // 32 KB  [n][k]
  short* XWT = (short*)(ws + (64<<10));             // 2 MB   [128][M] bf16
  short* SPT = (short*)(ws + (64<<10) + (2<<20));   // 2 MB   [128][M] bf16
  short* H1  = (short*)(ws + (64<<10) + (4<<20));   // 2 MB   [M][128] bf16
  float* P   = (float*)(ws + (64<<10) + (6<<20));   // 16 MB  f32 [4][M][128]

  dim3 b(256);
  dim3 gbig(M/128, 4);       // 64 x 4 = 256 blocks, 1/CU
  dim3 gns(M/32);            // small K=128 GEMM
  dim3 grt(M/64);            // red_t
  dim3 grr(M*128/(256*8));   // red_r
  dim3 grf(M*128/(256*4));   // red_f
  dim3 gt(128);

  wtrans_k<<<gt, b, 0, stream>>>(W1, W2, W1T, W2T);
  // layer 1
  sgemm<false><<<gns, b, 0, stream>>>(input, W1T, XWT, 128, M);
  gemm_big<<<gbig, b, 0, stream>>>(winv, XWT, P, M, M);
  red_t  <<<grt, b, 0, stream>>>(P, f1, SPT, M);
  gemm_big<<<gbig, b, 0, stream>>>(wav, SPT, P, M, M);
  red_r  <<<grr, b, 0, stream>>>(P, H1, M);
  // layer 2
  sgemm<true ><<<gns, b, 0, stream>>>(H1, W2T, XWT, 128, M);
  gemm_big<<<gbig, b, 0, stream>>>(winv, XWT, P, M, M);
  red_t  <<<grt, b, 0, stream>>>(P, f2, SPT, M);
  gemm_big<<<gbig, b, 0, stream>>>(wav, SPT, P, M, M);
  red_f  <<<grf, b, 0, stream>>>(P, (float*)d_out, M);
}